// Round 17
// baseline (173.210 us; speedup 1.0000x reference)
//
#include <hip/hip_runtime.h>
#include <hip/hip_bf16.h>
#include <cstdint>

#define IN_CH 512
#define OUT_CH 512
#define STYLE_DIM 512
#define BATCH 8
#define HW 64

typedef __bf16 bf16x8 __attribute__((ext_vector_type(8)));
typedef float f32x16 __attribute__((ext_vector_type(16)));

__device__ __forceinline__ void gload_lds16(const void* g, void* l) {
  __builtin_amdgcn_global_load_lds(
      (const __attribute__((address_space(1))) unsigned int*)g,
      (__attribute__((address_space(3))) unsigned int*)l,
      16, 0, 0);
}

#define WAITV(N) asm volatile("s_waitcnt vmcnt(" #N ")" ::: "memory")
#define BARRIER() do { asm volatile("" ::: "memory"); __builtin_amdgcn_s_barrier(); \
                       asm volatile("" ::: "memory"); } while (0)

// xgp layout: [b][chunk8][yidx 0..65][slot8][col 0..65][8 ic]
//   yidx = image y + 1 (rows 0,65 = zeros); col = image x + 1 (cols 0,65 = zeros)
//   slot s holds ic = chunk*64 + s*8 .. +7  (s = ks*2 + laneK in the conv)
#define XSLOT 528            // 66 cols * 8 elem
#define XROW  4224           // 8 slots * XSLOT
#define XCHUNK (66 * 4224)   // 66 yidx rows

// ---------------- kernel 1: style-GEMM (0..127) | xgp zero rows (128..135) ---------------
__global__ void k_style(const float* __restrict__ style, const float* __restrict__ modw,
                        const float* __restrict__ modb, float* __restrict__ s_out,
                        __bf16* __restrict__ xgp) {
  const int tid = threadIdx.x;
  if (blockIdx.x >= 128) {            // zero yidx rows 0 and 65 for batch b
    const int b = blockIdx.x - 128;
    bf16x8 z = {};
    #pragma unroll
    for (int it = 0; it < 33; ++it) {
      const int u = it * 256 + tid;   // 8448 units
      const int chunk = u / 1056;
      const int rem = u - chunk * 1056;
      const int yidx = (rem / 528) * 65;
      const int rem2 = rem % 528;
      const int slot = rem2 / 66, col = rem2 % 66;
      *(bf16x8*)(xgp + ((size_t)(b * 8 + chunk) * XCHUNK + (size_t)yidx * XROW
                        + slot * XSLOT + col * 8)) = z;
    }
    return;
  }
  __shared__ float st[BATCH * STYLE_DIM];
  for (int i = tid; i < BATCH * STYLE_DIM; i += 256) st[i] = style[i];
  __syncthreads();
  const int ic = blockIdx.x * 4 + (tid >> 6);
  const int l = tid & 63;
  const float* mr = modw + (size_t)ic * STYLE_DIM + l * 8;
  float m[8];
  #pragma unroll
  for (int j = 0; j < 8; ++j) m[j] = mr[j];
  float accs[8];
  #pragma unroll
  for (int b = 0; b < 8; ++b) {
    const float* sb = st + b * STYLE_DIM + l * 8;
    float a = 0.f;
    #pragma unroll
    for (int j = 0; j < 8; ++j) a += m[j] * sb[j];
    accs[b] = a;
  }
  #pragma unroll
  for (int off = 32; off; off >>= 1) {
    #pragma unroll
    for (int b = 0; b < 8; ++b) accs[b] += __shfl_down(accs[b], off, 64);
  }
  if (l == 0) {
    #pragma unroll
    for (int b = 0; b < 8; ++b)
      s_out[b * IN_CH + ic] = accs[b] * 0.04419417382415922f + modb[ic];
  }
}

// ---------------- kernel 2 (fused): xprep | wprep(stripe) | demod ------------------------
__global__ void k_prep(const float* __restrict__ x, const float* __restrict__ s,
                       const float* __restrict__ w,
                       __bf16* __restrict__ xgp, __bf16* __restrict__ wgp,
                       float* __restrict__ scale) {
  const int t = threadIdx.x;
  const int bid = blockIdx.x;
  if (bid < 512) {
    const int b = bid >> 6, y = bid & 63;
    const int xcol = t & 63;          // image x; col = xcol+1
    const int g0 = t >> 6;            // 0..7
    const float* sr = s + b * IN_CH;
    #pragma unroll
    for (int i = 0; i < 8; ++i) {
      const int g = i * 8 + g0;       // chunk*8 + slot
      bf16x8 pk;
      #pragma unroll
      for (int e = 0; e < 8; ++e) {
        const int ic = g * 8 + e;
        pk[e] = (__bf16)(x[(((size_t)(b * IN_CH) + ic) * HW + y) * HW + xcol] * sr[ic]);
      }
      *(bf16x8*)(xgp + ((size_t)(b * 8 + (g >> 3)) * XCHUNK + (size_t)(y + 1) * XROW
                        + (g & 7) * XSLOT + (xcol + 1) * 8)) = pk;
    }
    if (t < 128) {                    // col halos 0 and 65 at this yidx
      const int col = (t & 1) * 65, g = t >> 1;
      bf16x8 z = {};
      *(bf16x8*)(xgp + ((size_t)(b * 8 + (g >> 3)) * XCHUNK + (size_t)(y + 1) * XROW
                        + (g & 7) * XSLOT + col * 8)) = z;
    }
  } else if (bid < 1024) {
    // wgp[tap][chunk8][octile2][2048 units]; unit (j,p): R=2j+(p&1), s=((p>>1)-j)&7
    const int idx = (bid - 512) * 512 + t;   // 262144
    const int oc = idx >> 9, ic = idx & 511;
    const int octile = oc >> 8, R = oc & 255, j = R >> 1;
    const int chunk = ic >> 6, sslot = (ic >> 3) & 7, e = ic & 7;
    const int p = 2 * ((sslot + j) & 7) + (R & 1);
    const int u = j * 16 + p;
    const float* pw = w + ((size_t)oc * IN_CH + ic) * 9;
    #pragma unroll
    for (int tp = 0; tp < 9; ++tp)
      wgp[((size_t)((tp * 8 + chunk) * 2 + octile) * 2048 + u) * 8 + e] = (__bf16)pw[tp];
  } else {
    // demod-direct
    const int oc = (bid - 1024) * 8 + (t >> 6);
    const int l = t & 63;
    float w8[8];
    #pragma unroll
    for (int j = 0; j < 8; ++j) {
      const float* pw = w + ((size_t)oc * IN_CH + l * 8 + j) * 9;
      float sum = 0.f;
      #pragma unroll
      for (int tp = 0; tp < 9; ++tp) { float v = pw[tp]; sum += v * v; }
      w8[j] = sum;
    }
    #pragma unroll
    for (int b = 0; b < 8; ++b) {
      const float* sb = s + b * IN_CH + l * 8;
      float acc = 0.f;
      #pragma unroll
      for (int j = 0; j < 8; ++j) { float sv = sb[j]; acc += sv * sv * w8[j]; }
      #pragma unroll
      for (int off = 32; off; off >>= 1) acc += __shfl_down(acc, off, 64);
      if (l == 0)
        scale[b * OUT_CH + oc] =
            rsqrtf(acc * (1.0f / 4608.0f) + 1e-8f) * 0.014731391274719732f;
    }
  }
}

// ---------------- main conv: W in LDS (stripe, conflict-free), X direct from global ------
// Removes all X LDS traffic (reads AND DMA writes) from the port: per tap LDS = 16 A-reads
// /wave + W-DMA ~ 1800 cyc < MFMA 2048 -> MFMA-bound. B = 8 global_load_dwordx4/wave/tap
// from L2-resident xgp (halos baked -> no bounds checks). 1 barrier/tap; W triple-buffered
// 2-deep; B loads issued pre-barrier, compiler auto-vmcnt gates each ks.
__global__ __launch_bounds__(512, 2) void k_conv(
    const __bf16* __restrict__ Wgp,  // [9][8][2][2048*8]
    const __bf16* __restrict__ Xgp,  // [8][8][66][8][66][8]
    const float* __restrict__ scale, // [8][512] = demod*cs
    float* __restrict__ out)         // [8][512][64][64]
{
  __shared__ __attribute__((aligned(16))) __bf16 Wl[3][2048 * 8];  // 98304 B total LDS

  const int tid = threadIdx.x;
  const int lane = tid & 63;
  const int wid = tid >> 6;
  const int wm = wid >> 2;      // oc half
  const int wn = wid & 3;       // image row within tile
  const int ln31 = lane & 31;
  const int laneK = lane >> 5;

  const int bid0 = blockIdx.x;
  const int bid = (bid0 & 7) * 32 + (bid0 >> 3);   // XCD-chunked: XCD x owns batch x
  const int octile = bid & 1;
  const int ptile = (bid >> 1) & 15;
  const int b = bid >> 5;
  const int r0 = ptile * 4;
  const int oc0 = octile * 256;

  auto stage_w = [&](int chunkv, int tapv, int bsel) {  // 4 units/thread, linear
    const __bf16* base = Wgp + (size_t)((tapv * 8 + chunkv) * 2 + octile) * (2048 * 8);
    #pragma unroll
    for (int i = 0; i < 4; ++i) {
      const int u = i * 512 + tid;
      gload_lds16(base + (size_t)u * 8, (void*)((char*)Wl[bsel] + u * 16));
    }
  };

  // prologue: W(0)->buf0, W(1)->buf1
  stage_w(0, 0, 0);
  stage_w(0, 1, 1);

  // ---- invariant addressing ----
  int aoff8[4];
  #pragma unroll
  for (int ks = 0; ks < 4; ++ks) aoff8[ks] = ((ln31 + 4 * ks + 2 * laneK) & 15) * 8;
  const __bf16* __restrict__ ab0 = Wl[0] + (64 * wm + (ln31 >> 1)) * 128;
  const __bf16* __restrict__ ab1 = Wl[1] + (64 * wm + (ln31 >> 1)) * 128;
  const __bf16* __restrict__ ab2 = Wl[2] + (64 * wm + (ln31 >> 1)) * 128;
  // B: per-wave row base (chunk 0), advanced by XCHUNK at each chunk boundary
  const __bf16* __restrict__ xrowb =
      Xgp + (size_t)(b * 8) * XCHUNK + (size_t)(r0 + wn) * XROW + laneK * XSLOT;
  int bcol[3];
  #pragma unroll
  for (int dxi = 0; dxi < 3; ++dxi) bcol[dxi] = (ln31 + dxi) * 8;

  f32x16 acc[4][2] = {};

#define TAPBODY(T) { \
    WAITV(4); \
    const __bf16* __restrict__ xr = xrowb + ((T) / 3) * XROW + bcol[(T) % 3]; \
    bf16x8 bv0[4], bv1[4]; \
    _Pragma("unroll") \
    for (int ks = 0; ks < 4; ++ks) { \
      const __bf16* p_ = xr + ks * (2 * XSLOT); \
      bv0[ks] = *(const bf16x8*)p_; \
      bv1[ks] = *(const bf16x8*)(p_ + 256); \
    } \
    BARRIER(); \
    { \
      int s2 = c * 9 + (T) + 2, c2 = s2 / 9, t2 = s2 - 9 * c2; \
      if (s2 >= 72) { c2 = 7; t2 = 8; }   /* dummy: keeps vmcnt uniform, buf unread */ \
      stage_w(c2, t2, ((T) + 2) % 3); \
    } \
    const __bf16* __restrict__ abase = ((T) % 3 == 0) ? ab0 : ((T) % 3 == 1) ? ab1 : ab2; \
    _Pragma("unroll") \
    for (int ks = 0; ks < 4; ++ks) { \
      bf16x8 av[4]; \
      _Pragma("unroll") \
      for (int mf = 0; mf < 4; ++mf) av[mf] = *(const bf16x8*)(abase + mf * 2048 + aoff8[ks]); \
      _Pragma("unroll") \
      for (int mf = 0; mf < 4; ++mf) { \
        acc[mf][0] = __builtin_amdgcn_mfma_f32_32x32x16_bf16(av[mf], bv0[ks], acc[mf][0], 0, 0, 0); \
        acc[mf][1] = __builtin_amdgcn_mfma_f32_32x32x16_bf16(av[mf], bv1[ks], acc[mf][1], 0, 0, 0); \
      } \
    } \
    if ((T) == 8) xrowb += XCHUNK; \
  }

  #pragma unroll 1
  for (int c = 0; c < 8; ++c) {
    TAPBODY(0) TAPBODY(1) TAPBODY(2)
    TAPBODY(3) TAPBODY(4) TAPBODY(5)
    TAPBODY(6) TAPBODY(7) TAPBODY(8)
  }

  // epilogue: out = acc * (demod*cs), NCHW
  const int y = r0 + wn;
  #pragma unroll
  for (int mf = 0; mf < 4; ++mf) {
    #pragma unroll
    for (int reg = 0; reg < 16; ++reg) {
      const int rowid = (reg & 3) + 8 * (reg >> 2) + 4 * laneK;
      const int oc = oc0 + 128 * wm + 32 * mf + rowid;
      const float sc = scale[b * OUT_CH + oc];
      float* op = out + (((size_t)(b * OUT_CH + oc) * HW + y) * HW) + ln31;
      op[0] = acc[mf][0][reg] * sc;
      op[32] = acc[mf][1][reg] * sc;
    }
  }
}

// ---------------- launcher ---------------------------------------------------------------
extern "C" void kernel_launch(void* const* d_in, const int* in_sizes, int n_in,
                              void* d_out, int out_size, void* d_ws, size_t ws_size,
                              hipStream_t stream) {
  const float* x      = (const float*)d_in[0];
  const float* style  = (const float*)d_in[1];
  const float* weight = (const float*)d_in[2];
  const float* modw   = (const float*)d_in[3];
  const float* modb   = (const float*)d_in[4];
  float* out = (float*)d_out;

  char* ws = (char*)d_ws;
  float*  s_buf = (float*)(ws + 0);                        // 16 KB
  float*  scale = (float*)(ws + 16384);                    // 16 KB
  __bf16* wgp   = (__bf16*)(ws + 32768);                   // 4.72 MB
  __bf16* xgp   = (__bf16*)(ws + 32768 + 9 * 8 * 2 * 2048 * 8 * 2);  // 35.7 MB

  k_style<<<136, 256, 0, stream>>>(style, modw, modb, s_buf, xgp);
  k_prep<<<1088, 512, 0, stream>>>(x, s_buf, weight, xgp, wgp, scale);
  k_conv<<<256, 512, 0, stream>>>(wgp, xgp, scale, out);
}